// Round 5
// baseline (479.622 us; speedup 1.0000x reference)
//
#include <hip/hip_runtime.h>

#define T_    8192
#define C_    1024
#define TCH   16             // timesteps per chunk (one phase-C wave per chunk)
#define CPB   4              // chunks per block (= superblock)
#define ROWS  (CPB * TCH)    // 64 timesteps per block
#define NSB   (T_ / ROWS)    // 128 superblocks per batch
#define BATCH 4              // timesteps per batched variance-reduce

typedef float v4f __attribute__((ext_vector_type(4)));

// ---------------------------------------------------------------------------
// Single-dispatch GMRNorm: per-block superblock sum + decoupled-lookback
// prefix + normalize. Grid (NSB, B) = 512 blocks <= resident capacity at
// launch_bounds(256,2), so lookback spin-wait cannot deadlock (and lookback
// only ever waits on lower block IDs, which dispatch earlier).
// ---------------------------------------------------------------------------
__global__ __launch_bounds__(256, 2) void k_all(const float* __restrict__ x,
                                                float* __restrict__ agg,
                                                float* __restrict__ inc,
                                                int*   __restrict__ flags,
                                                const float* __restrict__ w,
                                                float* __restrict__ out) {
    const int sb  = blockIdx.x;
    const int b   = blockIdx.y;
    const int tid = threadIdx.x;

    __shared__ float chunkpre[CPB][C_];   // exclusive chunk prefixes (16 KB)
    __shared__ float pre2[C_];            // global prefix before superblock (4 KB)

    // ---------------- phase A: superblock channel sums --------------------
    const int c4 = tid * 4;
    const float* xp = x + ((size_t)(b * T_ + sb * ROWS)) * C_ + c4;
    float4 run = make_float4(0.f, 0.f, 0.f, 0.f);
#pragma unroll
    for (int j = 0; j < CPB; ++j) {
        *(float4*)&chunkpre[j][c4] = run;          // exclusive within superblock
#pragma unroll
        for (int i = 0; i < TCH; ++i) {
            float4 v = *(const float4*)(xp + (size_t)(j * TCH + i) * C_);
            run.x += v.x; run.y += v.y; run.z += v.z; run.w += v.w;
        }
    }

    // ---------------- phase B: publish + decoupled lookback ---------------
    const size_t tile = (size_t)b * NSB + sb;
    float4 excl = make_float4(0.f, 0.f, 0.f, 0.f);

    if (sb > 0) {
        *(float4*)(agg + tile * C_ + c4) = run;
        __syncthreads();                           // all payload stores drained
        if (tid == 0)
            __hip_atomic_store(&flags[tile], 1, __ATOMIC_RELEASE,
                               __HIP_MEMORY_SCOPE_AGENT);
        // per-thread independent backward walk (threads may diverge; each
        // thread's accumulation is independently correct: flags are monotonic
        // 0 -> 1(agg valid) -> 2(inc valid))
        int t = sb - 1;
        while (true) {
            const size_t pt = (size_t)b * NSB + t;
            int f;
            do {
                f = __hip_atomic_load(&flags[pt], __ATOMIC_ACQUIRE,
                                      __HIP_MEMORY_SCOPE_AGENT);
            } while (f == 0);
            const float* src = (f == 2 ? inc : agg) + pt * C_ + c4;
            float4 v = *(const float4*)src;
            excl.x += v.x; excl.y += v.y; excl.z += v.z; excl.w += v.w;
            if (f == 2 || t == 0) break;           // tile 0 only publishes 2
            --t;
        }
        float4 iv = make_float4(excl.x + run.x, excl.y + run.y,
                                excl.z + run.z, excl.w + run.w);
        *(float4*)(inc + tile * C_ + c4) = iv;
    } else {
        *(float4*)(inc + tile * C_ + c4) = run;    // inclusive == aggregate
    }
    *(float4*)&pre2[c4] = excl;
    __syncthreads();                               // inc stores + LDS ready
    if (tid == 0)
        __hip_atomic_store(&flags[tile], 2, __ATOMIC_RELEASE,
                           __HIP_MEMORY_SCOPE_AGENT);

    // ---------------- phase C: normalize (x re-read is L2/L3-hot) ---------
    const int wave = tid >> 6;
    const int lane = tid & 63;
    const int ch   = sb * CPB + wave;
    const int cb   = lane * 4;

    float4 racc[4], wt[4];
#pragma unroll
    for (int q = 0; q < 4; ++q) {
        float4 p2 = *(const float4*)&pre2[q * 256 + cb];
        float4 cp = *(const float4*)&chunkpre[wave][q * 256 + cb];
        racc[q] = make_float4(p2.x + cp.x, p2.y + cp.y, p2.z + cp.z, p2.w + cp.w);
        wt[q]   = *(const float4*)(w + q * 256 + cb);
    }

    const int t0 = ch * TCH;
    const float* xq = x   + (size_t)(b * T_ + t0) * C_;
    float*       op = out + (size_t)(b * T_ + t0) * C_;
    const float invC = 1.0f / (float)C_;

#pragma unroll
    for (int h = 0; h < TCH / BATCH; ++h) {
        float4 xc[BATCH][4];
        float  sq[BATCH];

#pragma unroll
        for (int i = 0; i < BATCH; ++i) {
            const int tt = t0 + h * BATCH + i;
            const float m = (tt == 0) ? 0.0f
                                      : __builtin_amdgcn_rcpf((float)(tt + 1));
            float s = 0.f;
#pragma unroll
            for (int q = 0; q < 4; ++q) {
                float4 v = *(const float4*)(xq + (size_t)(h * BATCH + i) * C_
                                               + q * 256 + cb);
                racc[q].x += v.x; float a0 = v.x - racc[q].x * m; s += a0 * a0;
                racc[q].y += v.y; float a1 = v.y - racc[q].y * m; s += a1 * a1;
                racc[q].z += v.z; float a2 = v.z - racc[q].z * m; s += a2 * a2;
                racc[q].w += v.w; float a3 = v.w - racc[q].w * m; s += a3 * a3;
                xc[i][q] = make_float4(a0, a1, a2, a3);
            }
            sq[i] = s;
        }

#pragma unroll
        for (int off = 32; off; off >>= 1) {
#pragma unroll
            for (int i = 0; i < BATCH; ++i)
                sq[i] += __shfl_xor(sq[i], off, 64);
        }

        float scale[BATCH];
#pragma unroll
        for (int i = 0; i < BATCH; ++i)
            scale[i] = __builtin_amdgcn_rsqf(sq[i] * invC + 1e-5f);

#pragma unroll
        for (int i = 0; i < BATCH; ++i) {
#pragma unroll
            for (int q = 0; q < 4; ++q) {
                v4f o;
                o.x = wt[q].x * xc[i][q].x * scale[i];
                o.y = wt[q].y * xc[i][q].y * scale[i];
                o.z = wt[q].z * xc[i][q].z * scale[i];
                o.w = wt[q].w * xc[i][q].w * scale[i];
                __builtin_nontemporal_store(o,
                    (v4f*)(op + (size_t)(h * BATCH + i) * C_ + q * 256 + cb));
            }
        }
    }
}

extern "C" void kernel_launch(void* const* d_in, const int* in_sizes, int n_in,
                              void* d_out, int out_size, void* d_ws, size_t ws_size,
                              hipStream_t stream) {
    const float* x = (const float*)d_in[0];
    const float* w = (const float*)d_in[1];
    float* out = (float*)d_out;

    const int B = in_sizes[0] / (T_ * C_);            // 4

    float* agg   = (float*)d_ws;                      // B*NSB*C = 2 MB
    float* inc   = agg + (size_t)B * NSB * C_;        // 2 MB
    int*   flags = (int*)(inc + (size_t)B * NSB * C_);// B*NSB ints = 2 KB

    hipMemsetAsync(flags, 0, (size_t)B * NSB * sizeof(int), stream);

    dim3 g(NSB, B);                                   // 512 blocks, co-resident
    k_all<<<g, 256, 0, stream>>>(x, agg, inc, flags, w, out);
}

// Round 7
// 257.833 us; speedup vs baseline: 1.8602x; 1.8602x over previous
//
#include <hip/hip_runtime.h>

#define T_    8192
#define C_    1024
#define TCH   16             // timesteps per chunk (one K2 wave per chunk)
#define NCH   (T_ / TCH)     // 512 chunks
#define CPB   4              // chunks per block (= superblock)
#define ROWS  (CPB * TCH)    // 64 timesteps per block
#define NSB   (T_ / ROWS)    // 128 superblocks
#define BATCH 4              // timesteps per batched variance-reduce

typedef float v4f __attribute__((ext_vector_type(4)));

// ---------------------------------------------------------------------------
// K1: one pass over x. Block (sb,b) = 64 timesteps x 1024 ch. Writes
// per-chunk channel sums Scs[b][ch][c] and superblock totals agg[b][sb][c].
// No prefixes here -- K2 derives them; no cross-block communication anywhere
// (R2/R6 post-mortem: in-kernel lookback/coop sync kills this harness).
// ---------------------------------------------------------------------------
__global__ __launch_bounds__(256) void k_sums(const float* __restrict__ x,
                                              float* __restrict__ Scs,
                                              float* __restrict__ agg) {
    const int sb = blockIdx.x;
    const int b  = blockIdx.y;
    const int c4 = threadIdx.x * 4;
    const float* xp = x + ((size_t)(b * T_ + sb * ROWS)) * C_ + c4;
    float* Sp = Scs + ((size_t)(b * NCH + sb * CPB)) * C_ + c4;

    float4 tot = make_float4(0.f, 0.f, 0.f, 0.f);
#pragma unroll
    for (int j = 0; j < CPB; ++j) {
        float4 cs = make_float4(0.f, 0.f, 0.f, 0.f);
#pragma unroll
        for (int i = 0; i < TCH; ++i) {           // 16 independent loads (ILP)
            float4 v = *(const float4*)(xp + (size_t)(j * TCH + i) * C_);
            cs.x += v.x; cs.y += v.y; cs.z += v.z; cs.w += v.w;
        }
        *(float4*)(Sp + (size_t)j * C_) = cs;     // chunk sum
        tot.x += cs.x; tot.y += cs.y; tot.z += cs.z; tot.w += cs.w;
    }
    *(float4*)(agg + ((size_t)(b * NSB + sb)) * C_ + c4) = tot;
}

// ---------------------------------------------------------------------------
// K2: block (sb,b) = superblock. Global prefix = sum of predecessor agg rows
// (2 MB buffer, L2-resident, coalesced 4KB rows -- kernel boundary makes
// them all valid, no flags). Wave w adds its <=3 intra-superblock chunk-sum
// rows, then normalizes its 16 timesteps: batched prefix-accumulate/center/
// partial-sq, 4 overlapped 6-deep butterflies, v_rsq, nontemporal stores.
// x re-read is L3-hot (R5 measured: FETCH 143 MB for both passes combined).
// ---------------------------------------------------------------------------
__global__ __launch_bounds__(256) void k_norm(const float* __restrict__ x,
                                              const float* __restrict__ Scs,
                                              const float* __restrict__ agg,
                                              const float* __restrict__ w,
                                              float* __restrict__ out) {
    const int sb  = blockIdx.x;
    const int b   = blockIdx.y;
    const int tid = threadIdx.x;
    const int c4  = tid * 4;

    __shared__ float pre2[C_];                    // prefix before superblock

    // ---- cooperative sum of predecessor superblock totals ----
    float4 excl = make_float4(0.f, 0.f, 0.f, 0.f);
    const float* ap = agg + (size_t)b * NSB * C_ + c4;
#pragma unroll 4
    for (int j = 0; j < sb; ++j) {                // coalesced, L2-hit, ILP-rich
        float4 v = *(const float4*)(ap + (size_t)j * C_);
        excl.x += v.x; excl.y += v.y; excl.z += v.z; excl.w += v.w;
    }
    *(float4*)&pre2[c4] = excl;
    __syncthreads();

    // ---- per-wave prefix: pre2 + chunk sums before this wave's chunk ----
    const int wave = tid >> 6;
    const int lane = tid & 63;
    const int ch   = sb * CPB + wave;
    const int cb   = lane * 4;
    const float* Sp = Scs + ((size_t)(b * NCH + sb * CPB)) * C_;

    float4 racc[4], wt[4];
#pragma unroll
    for (int q = 0; q < 4; ++q) {
        float4 p2 = *(const float4*)&pre2[q * 256 + cb];
        racc[q] = p2;
        for (int j = 0; j < wave; ++j) {          // wave-uniform trip count
            float4 s = *(const float4*)(Sp + (size_t)j * C_ + q * 256 + cb);
            racc[q].x += s.x; racc[q].y += s.y; racc[q].z += s.z; racc[q].w += s.w;
        }
        wt[q] = *(const float4*)(w + q * 256 + cb);
    }

    // ---- normalize 16 timesteps ----
    const int t0 = ch * TCH;
    const float* xq = x   + (size_t)(b * T_ + t0) * C_;
    float*       op = out + (size_t)(b * T_ + t0) * C_;
    const float invC = 1.0f / (float)C_;

#pragma unroll
    for (int h = 0; h < TCH / BATCH; ++h) {
        float4 xc[BATCH][4];
        float  sq[BATCH];

#pragma unroll
        for (int i = 0; i < BATCH; ++i) {
            const int tt = t0 + h * BATCH + i;
            const float m = (tt == 0) ? 0.0f
                                      : __builtin_amdgcn_rcpf((float)(tt + 1));
            float s = 0.f;
#pragma unroll
            for (int q = 0; q < 4; ++q) {
                float4 v = *(const float4*)(xq + (size_t)(h * BATCH + i) * C_
                                               + q * 256 + cb);
                racc[q].x += v.x; float a0 = v.x - racc[q].x * m; s += a0 * a0;
                racc[q].y += v.y; float a1 = v.y - racc[q].y * m; s += a1 * a1;
                racc[q].z += v.z; float a2 = v.z - racc[q].z * m; s += a2 * a2;
                racc[q].w += v.w; float a3 = v.w - racc[q].w * m; s += a3 * a3;
                xc[i][q] = make_float4(a0, a1, a2, a3);
            }
            sq[i] = s;
        }

#pragma unroll
        for (int off = 32; off; off >>= 1) {
#pragma unroll
            for (int i = 0; i < BATCH; ++i)
                sq[i] += __shfl_xor(sq[i], off, 64);
        }

        float scale[BATCH];
#pragma unroll
        for (int i = 0; i < BATCH; ++i)
            scale[i] = __builtin_amdgcn_rsqf(sq[i] * invC + 1e-5f);

#pragma unroll
        for (int i = 0; i < BATCH; ++i) {
#pragma unroll
            for (int q = 0; q < 4; ++q) {
                v4f o;
                o.x = wt[q].x * xc[i][q].x * scale[i];
                o.y = wt[q].y * xc[i][q].y * scale[i];
                o.z = wt[q].z * xc[i][q].z * scale[i];
                o.w = wt[q].w * xc[i][q].w * scale[i];
                __builtin_nontemporal_store(o,
                    (v4f*)(op + (size_t)(h * BATCH + i) * C_ + q * 256 + cb));
            }
        }
    }
}

extern "C" void kernel_launch(void* const* d_in, const int* in_sizes, int n_in,
                              void* d_out, int out_size, void* d_ws, size_t ws_size,
                              hipStream_t stream) {
    const float* x = (const float*)d_in[0];
    const float* w = (const float*)d_in[1];
    float* out = (float*)d_out;

    const int B = in_sizes[0] / (T_ * C_);            // 4

    float* Scs = (float*)d_ws;                        // B*NCH*C floats = 8 MB
    float* agg = Scs + (size_t)B * NCH * C_;          // B*NSB*C floats = 2 MB

    dim3 g(NSB, B);                                   // 512 blocks each
    k_sums<<<g, 256, 0, stream>>>(x, Scs, agg);
    k_norm<<<g, 256, 0, stream>>>(x, Scs, agg, w, out);
}